// Round 2
// baseline (2391.153 us; speedup 1.0000x reference)
//
#include <hip/hip_runtime.h>

#define TWO_PI 6.2831853071795864769f
#define SP3 327680      // 128*128*20
#define YT 2560         // 128*20

static __device__ __forceinline__ float gelu_f(float u){
  return 0.5f*u*(1.0f+erff(u*0.7071067811865475f));
}

// ---------------- fc0: x(B,X,Y,T,5) @ (5,20) + b -> h(B,32stride,X,Y,T), 20 ch ----
__global__ void k_fc0(const float* __restrict__ x, const float* __restrict__ w,
                      const float* __restrict__ bias, float* __restrict__ h){
  __shared__ float wl[100], bl[20];
  int tid=threadIdx.x;
  if(tid<100) wl[tid]=w[tid];
  if(tid<20) bl[tid]=bias[tid];
  __syncthreads();
  int p=blockIdx.x*256+tid;          // 0..1310719
  int b=p/SP3, sp=p-b*SP3;
  const float* xp=x+(long)p*5;
  float xi[5];
  #pragma unroll
  for(int i=0;i<5;i++) xi[i]=xp[i];
  float* hb=h+(long)(b*32)*SP3+sp;
  #pragma unroll
  for(int c=0;c<20;c++){
    float a=bl[c];
    #pragma unroll
    for(int i=0;i<5;i++) a+=xi[i]*wl[i*20+c];
    hb[(long)c*SP3]=a;
  }
}

// ------------- forward T+Y DFT: per (b,c,x) row slab -> Fty[(b*32+c)*128+x, slot2, kz] complex
__global__ void k_fwd_ty(const float* __restrict__ h, float* __restrict__ Fty,
                         int Ci, int m2){
  int bid=blockIdx.x;
  int xx=bid&127; int bc=bid>>7; int c=bc%Ci; int b=bc/Ci;
  int J=2*m2*8;
  __shared__ float slab[2560];
  __shared__ float Gre[1024], Gim[1024];
  __shared__ float c20[20],s20[20],c128[128],s128[128];
  int tid=threadIdx.x;
  if(tid<128){ float s,cc; sincosf(TWO_PI*tid/128.0f,&s,&cc); c128[tid]=cc; s128[tid]=s; }
  if(tid<20){ float s,cc; sincosf(TWO_PI*tid/20.0f,&s,&cc); c20[tid]=cc; s20[tid]=s; }
  const float* hb=h+(long)(b*32+c)*SP3+xx*YT;
  for(int i=tid;i<2560;i+=256) slab[i]=hb[i];
  __syncthreads();
  // T-DFT: G[y][kz] = sum_t slab[y][t] * e^{-2pi i kz t/20}
  for(int idx=tid;idx<1024;idx+=256){
    int y=idx>>3, kz=idx&7;
    const float* row=slab+y*20;
    float re=0.f, im=0.f;
    for(int t=0;t<20;t++){
      int j=(kz*t)%20; float v=row[t];
      re+=v*c20[j]; im-=v*s20[j];
    }
    Gre[idx]=re; Gim[idx]=im;
  }
  __syncthreads();
  // Y-DFT: out[slot,kz] = sum_y G[y][kz] * e^{-2pi i ky y/128}
  float* outp=Fty+((long)(b*32+c)*128+xx)*J*2;
  for(int idx=tid;idx<J;idx+=256){
    int slot=idx>>3, kz=idx&7;
    int km=(slot<m2)?slot:(slot-2*m2);
    float re=0.f, im=0.f;
    for(int y=0;y<128;y++){
      int j=(km*y)&127; float cc=c128[j], ss=s128[j];
      float ar=Gre[y*8+kz], ai=Gim[y*8+kz];
      re+=ar*cc+ai*ss;
      im+=ai*cc-ar*ss;
    }
    outp[idx*2]=re; outp[idx*2+1]=im;
  }
}

// ------------- forward X DFT: Fty[(b*32+c)*128+x, J] -> Fm[(b*32+c), slot1, J]
template<int M1>
__global__ void k_fwd_x(const float* __restrict__ Fty, float* __restrict__ Fm,
                        int Ci, int m2){
  int bid=blockIdx.x; int c=bid%Ci; int b=bid/Ci;
  int J=2*m2*8;
  __shared__ float tile[32*192*2];
  __shared__ float c128[128], s128[128];
  int tid=threadIdx.x;
  if(tid<128){ float s,cc; sincosf(TWO_PI*tid/128.0f,&s,&cc); c128[tid]=cc; s128[tid]=s; }
  float accre[2*M1], accim[2*M1];
  #pragma unroll
  for(int s=0;s<2*M1;s++){accre[s]=0.f;accim[s]=0.f;}
  for(int xt=0;xt<4;xt++){
    __syncthreads();
    const float* src=Fty+((long)(b*32+c)*128+xt*32)*J*2;
    for(int i=tid;i<32*J*2;i+=256) tile[i]=src[i];
    __syncthreads();
    if(tid<J){
      for(int xl=0;xl<32;xl++){
        int xg=xt*32+xl;
        float ar=tile[(xl*J+tid)*2], ai=tile[(xl*J+tid)*2+1];
        #pragma unroll
        for(int s=0;s<2*M1;s++){
          int km=(s<M1)?s:(s-2*M1);
          int j=(km*xg)&127; float cc=c128[j], ss=s128[j];
          accre[s]+=ar*cc+ai*ss;
          accim[s]+=ai*cc-ar*ss;
        }
      }
    }
  }
  if(tid<J){
    float* o=Fm+(long)(b*32+c)*(2*M1)*J*2;
    #pragma unroll
    for(int s=0;s<2*M1;s++){
      o[(s*J+tid)*2]=accre[s];
      o[(s*J+tid)*2+1]=accim[s];
    }
  }
}

// ------------- mode mixing: Fm[(b*32+i),slots] x w(4,2,Ci,Co,m1,m2,8) -> Fm2[(b*32+o),slots]
__global__ void k_mix(const float* __restrict__ Fm, const float* __restrict__ w,
                      float* __restrict__ Fm2, int Ci, int Co, int m1, int m2){
  int MC=m1*m2*8;
  int nch=MC/8;
  int bid=blockIdx.x;
  int chunk=bid%nch; int q=(bid/nch)&3; int b=bid/(4*nch);
  int tid=threadIdx.x;
  int M1S=2*m1, M2S=2*m2;
  int J=M2S*8;
  __shared__ float fin[32*16];
  for(int idx=tid;idx<Ci*16;idx+=blockDim.x){
    int i=idx>>4; int r=idx&15; int mll=r>>1; int ri=r&1;
    int mg=chunk*8+mll;
    int mx=mg/(m2*8); int my=(mg>>3)%m2; int kz=mg&7;
    int sx=(q&1)?(m1+mx):mx; int sy=(q&2)?(m2+my):my;
    fin[idx]=Fm[((long)((b*32+i)*M1S+sx)*J+sy*8+kz)*2+ri];
  }
  __syncthreads();
  int ml=tid&7, o=tid>>3;
  int mg=chunk*8+ml;
  int mx=mg/(m2*8); int my=(mg>>3)%m2; int kz=mg&7;
  int sx=(q&1)?(m1+mx):mx; int sy=(q&2)?(m2+my):my;
  int moff=(mx*m2+my)*8+kz;
  const float* wr=w+(long)(q*2)*Ci*Co*MC+o*MC+moff;
  const float* wi=wr+(long)Ci*Co*MC;
  long wstep=(long)Co*MC;
  float re=0.f, im=0.f;
  for(int i=0;i<Ci;i++){
    float ar=fin[i*16+ml*2], ai=fin[i*16+ml*2+1];
    float wrv=wr[i*wstep], wiv=wi[i*wstep];
    re+=ar*wrv-ai*wiv;
    im+=ar*wiv+ai*wrv;
  }
  long oidx=((long)((b*32+o)*M1S+sx)*J+sy*8+kz)*2;
  Fm2[oidx]=re; Fm2[oidx+1]=im;
}

// ------------- inverse X: Fm2[(b*32+o),slot1,J] -> g1[(b*32+o)*128+x, J]
__global__ void k_inv_x(const float* __restrict__ Fm2, float* __restrict__ g1,
                        int Co, int m1, int m2){
  int bid=blockIdx.x; int xt=bid&3; int oc=(bid>>2)%Co; int b=bid/(4*Co);
  int M1S=2*m1; int J=2*m2*8;
  __shared__ float slab[24*192*2];
  __shared__ float c128[128], s128[128];
  int tid=threadIdx.x;
  if(tid<128){ float s,cc; sincosf(TWO_PI*tid/128.0f,&s,&cc); c128[tid]=cc; s128[tid]=s; }
  const float* src=Fm2+(long)(b*32+oc)*M1S*J*2;
  for(int i=tid;i<M1S*J*2;i+=256) slab[i]=src[i];
  __syncthreads();
  for(int out=tid;out<32*J;out+=256){
    int xl=out/J; int j=out-xl*J; int xg=xt*32+xl;
    float re=0.f, im=0.f;
    for(int s=0;s<M1S;s++){
      int km=(s<m1)?s:(s-2*m1);
      int jj=(km*xg)&127; float cc=c128[jj], ss=s128[jj];
      float ar=slab[(s*J+j)*2], ai=slab[(s*J+j)*2+1];
      re+=ar*cc-ai*ss;
      im+=ar*ss+ai*cc;
    }
    long oidx=((long)((b*32+oc)*128+xg)*J+j)*2;
    g1[oidx]=re; g1[oidx+1]=im;
  }
}

// ------------- pointwise conv IN-PLACE: h[b,o,sp] = bias[o] + sum_i h[b,i,sp]*w[o,i]
// Safe in-place: each thread owns one sp column; all reads precede all writes.
template<int CO>
__global__ void k_pconv(float* h, const float* __restrict__ w,
                        const float* __restrict__ bias, int Ci){
  __shared__ float wl[CO*32]; __shared__ float bl[CO];
  int tid=threadIdx.x;
  for(int i=tid;i<CO*Ci;i+=256) wl[i]=w[i];
  if(tid<CO) bl[tid]=bias[tid];
  __syncthreads();
  int p=blockIdx.x*256+tid;
  int b=p/SP3, sp=p-b*SP3;
  float acc[CO];
  #pragma unroll
  for(int o=0;o<CO;o++) acc[o]=bl[o];
  float* hb=h+(long)(b*32)*SP3+sp;
  for(int i=0;i<Ci;i++){
    float v=hb[(long)i*SP3];
    #pragma unroll
    for(int o=0;o<CO;o++) acc[o]+=v*wl[o*Ci+i];
  }
  #pragma unroll
  for(int o=0;o<CO;o++) hb[(long)o*SP3]=acc[o];
}

// ------------- inverse Y + inverse T + add into h + (gelu): per (b,o,x)
__global__ void k_inv_yt(const float* __restrict__ g1, float* __restrict__ hB,
                         int Co, int m2, int do_gelu){
  int bid=blockIdx.x; int xx=bid&127; int oc=(bid>>7)%Co; int b=bid/(128*Co);
  int J=2*m2*8;
  __shared__ float g1s[192*2];
  __shared__ float gyre[1024], gyim[1024];
  __shared__ float c20[20],s20[20],c128[128],s128[128];
  int tid=threadIdx.x;
  if(tid<128){ float s,cc; sincosf(TWO_PI*tid/128.0f,&s,&cc); c128[tid]=cc; s128[tid]=s; }
  if(tid<20){ float s,cc; sincosf(TWO_PI*tid/20.0f,&s,&cc); c20[tid]=cc; s20[tid]=s; }
  const float* src=g1+((long)(b*32+oc)*128+xx)*J*2;
  for(int i=tid;i<J*2;i+=256) g1s[i]=src[i];
  __syncthreads();
  int M2S=2*m2;
  for(int idx=tid;idx<1024;idx+=256){
    int y=idx>>3, kz=idx&7;
    float re=0.f, im=0.f;
    for(int s=0;s<M2S;s++){
      int km=(s<m2)?s:(s-2*m2);
      int j=(km*y)&127; float cc=c128[j], ss=s128[j];
      float ar=g1s[(s*8+kz)*2], ai=g1s[(s*8+kz)*2+1];
      re+=ar*cc-ai*ss;
      im+=ar*ss+ai*cc;
    }
    gyre[idx]=re; gyim[idx]=im;
  }
  __syncthreads();
  const float invN=1.0f/(128.0f*128.0f*20.0f);
  float* hb=hB+(long)(b*32+oc)*SP3+xx*YT;
  for(int idx=tid;idx<2560;idx+=256){
    int y=idx/20, t=idx-y*20;
    const float* gr=&gyre[y*8]; const float* gi=&gyim[y*8];
    float v=gr[0];
    #pragma unroll
    for(int kz=1;kz<8;kz++){
      int j=(kz*t)%20;
      v+=2.0f*(gr[kz]*c20[j]-gi[kz]*s20[j]);
    }
    float u=hb[idx]+v*invN;
    if(do_gelu) u=gelu_f(u);
    hb[idx]=u;
  }
}

// ------------- head: fc1(32->128)+gelu, fc2(128->3)
__global__ void k_head(const float* __restrict__ h, const float* __restrict__ w1,
                       const float* __restrict__ b1, const float* __restrict__ w2,
                       const float* __restrict__ b2, float* __restrict__ out){
  __shared__ float w1l[32*128], b1l[128], w2l[384], b2l[3];
  int tid=threadIdx.x;
  for(int i=tid;i<32*128;i+=256) w1l[i]=w1[i];
  if(tid<128) b1l[tid]=b1[tid];
  if(tid<3) b2l[tid]=b2[tid];
  for(int i=tid;i<384;i+=256) w2l[i]=w2[i];
  __syncthreads();
  int p=blockIdx.x*256+tid;
  int b=p/SP3, sp=p-b*SP3;
  const float* hb=h+(long)(b*32)*SP3+sp;
  float hv[32];
  #pragma unroll
  for(int i=0;i<32;i++) hv[i]=hb[(long)i*SP3];
  float a0=b2l[0], a1=b2l[1], a2=b2l[2];
  for(int jj=0;jj<128;jj++){
    float u=b1l[jj];
    #pragma unroll
    for(int i=0;i<32;i++) u+=hv[i]*w1l[i*128+jj];
    u=gelu_f(u);
    a0+=u*w2l[jj*3+0]; a1+=u*w2l[jj*3+1]; a2+=u*w2l[jj*3+2];
  }
  float* op=out+(long)p*3;
  op[0]=a0; op[1]=a1; op[2]=a2;
}

extern "C" void kernel_launch(void* const* d_in, const int* in_sizes, int n_in,
                              void* d_out, int out_size, void* d_ws, size_t ws_size,
                              hipStream_t stream){
  (void)in_sizes; (void)n_in; (void)out_size;
  const float* x    =(const float*)d_in[0];
  const float* fc0w =(const float*)d_in[1];
  const float* fc0b =(const float*)d_in[2];
  const float* sw[4]={(const float*)d_in[3],(const float*)d_in[6],(const float*)d_in[9],(const float*)d_in[12]};
  const float* cw[4]={(const float*)d_in[4],(const float*)d_in[7],(const float*)d_in[10],(const float*)d_in[13]};
  const float* cb[4]={(const float*)d_in[5],(const float*)d_in[8],(const float*)d_in[11],(const float*)d_in[14]};
  const float* fc1w =(const float*)d_in[15];
  const float* fc1b =(const float*)d_in[16];
  const float* fc2w =(const float*)d_in[17];
  const float* fc2b =(const float*)d_in[18];
  float* out=(float*)d_out;
  float* ws=(float*)d_ws;

  const long H_FLOATS   = 41943040L;            // 4*32*327680 (168 MB)
  const long FTY_FULL   = 6291456L;             // 4*32*128*192*2
  const long FM_FULL    = 1179648L;             // 4*32*24*192*2
  const long NEED_FULL  = H_FLOATS + FTY_FULL + 2*FM_FULL;  // 50,593,792 floats

  float* h = ws;                                // always: one activation buffer
  bool full = (ws_size >= (size_t)NEED_FULL*4);

  const int LAY[5]={20,24,24,32,32};
  const int M1A[4]={8,8,12,12};

  k_fc0<<<5120,256,0,stream>>>(x,fc0w,fc0b,h);

  for(int L=0;L<4;L++){
    int Ci=LAY[L], Co=LAY[L+1], m1=M1A[L], m2=M1A[L];
    int nch=m1*m2;
    long FM_B=(long)32*(2*m1)*(2*m2*8)*2;       // per-batch Fm/Fm2 stride

    if(full){
      float* Fty=ws+H_FLOATS;
      float* Fm =ws+H_FLOATS+FTY_FULL;
      float* Fm2=ws+H_FLOATS+FTY_FULL+FM_FULL;
      k_fwd_ty<<<4*Ci*128,256,0,stream>>>(h,Fty,Ci,m2);
      if(m1==8)  k_fwd_x<8> <<<4*Ci,256,0,stream>>>(Fty,Fm,Ci,m2);
      else       k_fwd_x<12><<<4*Ci,256,0,stream>>>(Fty,Fm,Ci,m2);
      k_mix<<<4*4*nch,Co*8,0,stream>>>(Fm,sw[L],Fm2,Ci,Co,m1,m2);
      if(Co==24) k_pconv<24><<<5120,256,0,stream>>>(h,cw[L],cb[L],Ci);
      else       k_pconv<32><<<5120,256,0,stream>>>(h,cw[L],cb[L],Ci);
      k_inv_x<<<4*Co*4,256,0,stream>>>(Fm2,Fty,Co,m1,m2);     // g1 aliases Fty
      k_inv_yt<<<4*Co*128,256,0,stream>>>(Fty,h,Co,m2,(L!=3)?1:0);
    } else {
      // scratch lives in d_out (rewritten entirely by k_head at the end)
      float* Fty=out;                 // <= 1,572,864 floats
      float* Fm =out+1572864;         // <=   294,912 floats
      float* Fm2=out+1867776;         // <= 4*294,912 = 1,179,648 floats (per-b strided)
      for(int b=0;b<4;b++){
        float* hbp=h+(long)b*32*SP3;
        k_fwd_ty<<<Ci*128,256,0,stream>>>(hbp,Fty,Ci,m2);
        if(m1==8)  k_fwd_x<8> <<<Ci,256,0,stream>>>(Fty,Fm,Ci,m2);
        else       k_fwd_x<12><<<Ci,256,0,stream>>>(Fty,Fm,Ci,m2);
        k_mix<<<4*nch,Co*8,0,stream>>>(Fm,sw[L],Fm2+b*FM_B,Ci,Co,m1,m2);
      }
      if(Co==24) k_pconv<24><<<5120,256,0,stream>>>(h,cw[L],cb[L],Ci);
      else       k_pconv<32><<<5120,256,0,stream>>>(h,cw[L],cb[L],Ci);
      for(int b=0;b<4;b++){
        float* hbp=h+(long)b*32*SP3;
        k_inv_x<<<Co*4,256,0,stream>>>(Fm2+b*FM_B,Fty,Co,m1,m2); // g1 aliases Fty
        k_inv_yt<<<Co*128,256,0,stream>>>(Fty,hbp,Co,m2,(L!=3)?1:0);
      }
    }
  }
  k_head<<<5120,256,0,stream>>>(h,fc1w,fc1b,fc2w,fc2b,out);
}